// Round 1
// baseline (1622.966 us; speedup 1.0000x reference)
//
#include <hip/hip_runtime.h>

typedef unsigned short u16;
typedef unsigned int u32;

#define N_USERS 100000
#define N_ITEMS 200000
#define N_NODES 300000
#define D 64
#define HYP 128
#define NNZ 4000000

// out is 96M fp32 elems: [user_out|item_out|gcn_hidden(2)|hgnn_hidden(2)]
constexpr long long SZL      = 19200000LL;        // one 300000x64 tensor
constexpr long long OUT_GCN0 = SZL;               // gcn_hidden base
constexpr long long OUT_HG0  = 3*SZL;             // hgnn_hidden base
// CSR {col,val} pairs overlaid on hgnn[l=1] region [4*SZL,5*SZL): written only
// by the final two GEMMs, which launch after the last SpMM read of the pairs.
// NNZ*8B = 32MB <= 76.8MB region. Single int2 store per edge => one dirty
// 64B line per edge instead of two (was separate col_s/val_s arrays).
constexpr long long OUT_PAIR = 4*SZL;

typedef __attribute__((ext_vector_type(8))) short short8;
typedef __attribute__((ext_vector_type(4))) float f32x4;

__device__ __forceinline__ float bf2f(u16 u){ u32 i = ((u32)u) << 16; return __builtin_bit_cast(float, i); }
__device__ __forceinline__ u16 f2bf(float f){
  u32 i = __builtin_bit_cast(u32, f);
  return (u16)((i + 0x7FFFu + ((i >> 16) & 1u)) >> 16);
}

// emb (fp32) -> h_bf (bf16), hsum (fp32, == out[0:SZL)). 8 elems/thread.
__global__ void k_init(const float* __restrict__ ue, const float* __restrict__ ie,
                       u16* __restrict__ h_bf, float* __restrict__ hsum){
  int t = blockIdx.x*256 + threadIdx.x;
  int base = t*8;
  const float* src = (base < N_USERS*D) ? (ue + base) : (ie + (base - N_USERS*D));
  float4 v0 = *(const float4*)(src);
  float4 v1 = *(const float4*)(src + 4);
  *(float4*)(hsum + base)     = v0;
  *(float4*)(hsum + base + 4) = v1;
  uint4 p;
  p.x = (u32)f2bf(v0.x) | ((u32)f2bf(v0.y)<<16);
  p.y = (u32)f2bf(v0.z) | ((u32)f2bf(v0.w)<<16);
  p.z = (u32)f2bf(v1.x) | ((u32)f2bf(v1.y)<<16);
  p.w = (u32)f2bf(v1.z) | ((u32)f2bf(v1.w)<<16);
  *(uint4*)(h_bf + base) = p;
}

// C[M x N] = A[M x K] @ B[K x N]; A bf16 row-major, B fp32 staged in LDS as bf16,
// C fp32 (C32) or bf16. 32 rows/block, 4 waves.
// FUSE (requires C32): also performs the layer epilogue on the same rows:
//   h = gcn + hg; hsum += h; hbf = bf16(h)   — saves re-reading hg from HBM.
template<int K, int N, bool C32, bool FUSE>
__global__ __launch_bounds__(256) void k_gemm_tall(const u16* __restrict__ A,
                                                   const float* __restrict__ B,
                                                   void* __restrict__ Cv,
                                                   const float* __restrict__ gcn,
                                                   float* __restrict__ hsum,
                                                   u16* __restrict__ hbf){
  constexpr int SROW = N + 2;                 // padded u16 stride (odd dword stride)
  __shared__ u32 blds[K*SROW/2];
  constexpr int PAIRS = K*N/2;
  for (int p = threadIdx.x; p < PAIRS; p += 256){
    int k = p/(N/2), c2 = p%(N/2);
    float f0 = B[2*p], f1 = B[2*p+1];
    blds[k*(SROW/2) + c2] = (u32)f2bf(f0) | ((u32)f2bf(f1)<<16);
  }
  __syncthreads();
  const u16* bl = (const u16*)blds;
  int wave = threadIdx.x>>6, lane = threadIdx.x&63, q = lane>>4, lm = lane&15;
  constexpr int NT = N/32;
  int mt = wave>>1, ntb = (wave&1)*NT;
  int r0 = blockIdx.x*32;
  f32x4 acc[NT];
  #pragma unroll
  for (int nt=0; nt<NT; ++nt) acc[nt] = (f32x4){0.f,0.f,0.f,0.f};
  const u16* arow = A + (size_t)(r0 + mt*16 + lm)*K + q*8;
  #pragma unroll
  for (int ks = 0; ks < K/32; ++ks){
    short8 a = *(const short8*)(arow + ks*32);
    #pragma unroll
    for (int nt = 0; nt < NT; ++nt){
      short8 b;
      #pragma unroll
      for (int j = 0; j < 8; ++j)
        b[j] = (short)bl[(ks*32 + q*8 + j)*SROW + (ntb+nt)*16 + lm];
      acc[nt] = __builtin_amdgcn_mfma_f32_16x16x32_bf16(a, b, acc[nt], 0, 0, 0);
    }
  }
  #pragma unroll
  for (int nt = 0; nt < NT; ++nt)
    #pragma unroll
    for (int r = 0; r < 4; ++r){
      int row = r0 + mt*16 + q*4 + r;       // C/D: col=lane&15, row=quad*4+reg (m89)
      int col = (ntb+nt)*16 + lm;
      size_t idx = (size_t)row*N + col;
      if (C32){
        float hg = acc[nt][r];
        ((float*)Cv)[idx] = hg;
        if (FUSE){
          float hv = gcn[idx] + hg;
          hsum[idx] += hv;
          hbf[idx] = f2bf(hv);
        }
      } else {
        ((u16*)Cv)[idx] = f2bf(acc[nt][r]);
      }
    }
}

// tmp[128x64] += Hyperᵀ[128 x rows] @ H[rows x 64] over a 512-row K-chunk per block.
__global__ __launch_bounds__(256) void k_step3(const u16* __restrict__ Hy,
                                               const u16* __restrict__ Hm,
                                               float* __restrict__ tmp, int rows){
  __shared__ u32 hyl[32*65];   // 32 k-rows x 128 elems, stride 130 u16
  __shared__ u32 hml[32*33];   // 32 k-rows x 64 elems,  stride 66 u16
  const u16* hyl16 = (const u16*)hyl;
  const u16* hml16 = (const u16*)hml;
  int tid = threadIdx.x;
  int wave = tid>>6, lane = tid&63, q = lane>>4, lm = lane&15;
  int k0 = blockIdx.x*512;
  f32x4 acc[2][4];
  #pragma unroll
  for (int i=0;i<2;i++)
    #pragma unroll
    for (int j=0;j<4;j++) acc[i][j] = (f32x4){0.f,0.f,0.f,0.f};
  for (int kk=0; kk<16; ++kk){
    int kb = k0 + kk*32;
    #pragma unroll
    for (int d0=0; d0<8; ++d0){
      int d = d0*256 + tid;
      int kr = d>>6, c2 = d&63, g = kb+kr;
      hyl[kr*65 + c2] = (g < rows) ? ((const u32*)Hy)[(size_t)g*64 + c2] : 0u;
    }
    #pragma unroll
    for (int d0=0; d0<4; ++d0){
      int d = d0*256 + tid;
      int kr = d>>5, c2 = d&31, g = kb+kr;
      hml[kr*33 + c2] = (g < rows) ? ((const u32*)Hm)[(size_t)g*32 + c2] : 0u;
    }
    __syncthreads();
    short8 a[2], b[4];
    #pragma unroll
    for (int ml=0; ml<2; ++ml)
      #pragma unroll
      for (int j=0;j<8;j++)
        a[ml][j] = (short)hyl16[(q*8+j)*130 + (wave*2+ml)*16 + lm];  // A[m][k]=Hy[k][m]
    #pragma unroll
    for (int nt=0; nt<4; ++nt)
      #pragma unroll
      for (int j=0;j<8;j++)
        b[nt][j] = (short)hml16[(q*8+j)*66 + nt*16 + lm];            // B[k][n]=Hm[k][n]
    #pragma unroll
    for (int ml=0; ml<2; ++ml)
      #pragma unroll
      for (int nt=0; nt<4; ++nt)
        acc[ml][nt] = __builtin_amdgcn_mfma_f32_16x16x32_bf16(a[ml], b[nt], acc[ml][nt], 0,0,0);
    __syncthreads();
  }
  #pragma unroll
  for (int ml=0; ml<2; ++ml)
    #pragma unroll
    for (int nt=0; nt<4; ++nt)
      #pragma unroll
      for (int r=0;r<4;r++){
        int m = (wave*2+ml)*16 + q*4 + r;
        int n = nt*16 + lm;
        atomicAdd(&tmp[m*64 + n], acc[ml][nt][r]);
      }
}

__global__ void k_hist(const int* __restrict__ rows_, int* __restrict__ cnt){
  int e = blockIdx.x*256 + threadIdx.x;
  if (e < NNZ){
    int r = rows_[e]; r = min(max(r,0), N_NODES-1);
    atomicAdd(&cnt[r], 1);
  }
}

__global__ __launch_bounds__(1024) void k_scan1(const int* __restrict__ cnt,
                                                int* __restrict__ rowptr, int* __restrict__ bsum){
  __shared__ int lds[1024];
  int i = blockIdx.x*1024 + threadIdx.x;
  int v = (i < N_NODES) ? cnt[i] : 0;
  lds[threadIdx.x] = v;
  for (int off=1; off<1024; off<<=1){
    __syncthreads();
    int add = (threadIdx.x >= off) ? lds[threadIdx.x-off] : 0;
    __syncthreads();
    lds[threadIdx.x] += add;
  }
  if (i < N_NODES) rowptr[i+1] = lds[threadIdx.x];
  if (threadIdx.x == 1023) bsum[blockIdx.x] = lds[1023];
}

__global__ __launch_bounds__(1024) void k_scan2(const int* __restrict__ bsum,
                                                int* __restrict__ boff, int nb){
  __shared__ int lds[1024];
  int t = threadIdx.x;
  int v = (t < nb) ? bsum[t] : 0;
  lds[t] = v;
  for (int off=1; off<1024; off<<=1){
    __syncthreads();
    int add = (t >= off) ? lds[t-off] : 0;
    __syncthreads();
    lds[t] += add;
  }
  if (t < nb) boff[t] = lds[t] - v;   // exclusive offsets
}

__global__ void k_scan3(const int* __restrict__ cnt, int* __restrict__ rowptr,
                        const int* __restrict__ boff, int* __restrict__ cursor){
  int i = blockIdx.x*256 + threadIdx.x;
  if (i == 0) rowptr[0] = 0;
  if (i < N_NODES){
    int inc = rowptr[i+1] + boff[i>>10];
    rowptr[i+1] = inc;
    cursor[i] = inc - cnt[i];
  }
}

// One 8B AoS store per edge: {col, val} packed as int2 -> one dirty 64B line
// per edge instead of two (col_s + val_s were separate random 4B stores).
__global__ void k_scatter(const int* __restrict__ rows_, const int* __restrict__ cols_,
                          const float* __restrict__ vals_, int* __restrict__ cursor,
                          int2* __restrict__ pair_s){
  int e = blockIdx.x*256 + threadIdx.x;
  if (e >= NNZ) return;
  int r = rows_[e]; r = min(max(r,0), N_NODES-1);
  int p = atomicAdd(&cursor[r], 1);
  p = min(max(p,0), NNZ-1);          // defensive: never write OOB
  pair_s[p] = make_int2(cols_[e], __float_as_int(vals_[e]));
}

// One wave per row; pairs read coalesced, broadcast via shfl so gathers pipeline.
__global__ __launch_bounds__(256) void k_spmm(const int* __restrict__ rp,
                                              const int2* __restrict__ ps,
                                              const u16* __restrict__ h,
                                              float* __restrict__ gout){
  int r = blockIdx.x*4 + (threadIdx.x>>6);
  int lane = threadIdx.x & 63;
  int beg = rp[r], end = rp[r+1];
  float acc = 0.f;
  for (int base = beg; base < end; base += 64){
    int c = 0; float v = 0.f;
    if (base + lane < end){ int2 pv = ps[base+lane]; c = pv.x; v = __int_as_float(pv.y); }
    int n = end - base; if (n > 64) n = 64;
    for (int e = 0; e < n; ++e){
      int ce = __shfl(c, e);
      float ve = __shfl(v, e);
      acc += ve * bf2f(h[(size_t)ce*64 + lane]);
    }
  }
  gout[(size_t)r*64 + lane] = acc;
}

extern "C" void kernel_launch(void* const* d_in, const int* in_sizes, int n_in,
                              void* d_out, int out_size, void* d_ws, size_t ws_size,
                              hipStream_t stream) {
  const float* user_emb = (const float*)d_in[0];
  const float* item_emb = (const float*)d_in[1];
  const float* user_w   = (const float*)d_in[2];
  const float* item_w   = (const float*)d_in[3];
  const float* adj_vals = (const float*)d_in[4];
  const int* adj_rows = (const int*)d_in[5];
  const int* adj_cols = (const int*)d_in[6];
  float* out = (float*)d_out;

  // ws usage (≈119 MB): hyper 76.8M + h_bf 38.4M + CSR misc ~3.7M
  char* w = (char*)d_ws;
  auto alloc = [&](size_t b){ void* p = (void*)w; w += (b + 255) & ~(size_t)255; return p; };
  u16*   hyper = (u16*)  alloc((size_t)N_NODES*HYP*2);
  u16*   h_bf  = (u16*)  alloc((size_t)N_NODES*D*2);
  int*   cnt   = (int*)  alloc((size_t)N_NODES*4);
  int*   cursor= (int*)  alloc((size_t)N_NODES*4);
  int*   rowptr= (int*)  alloc((size_t)(N_NODES+1)*4);
  int*   bsum  = (int*)  alloc(1024*4);
  int*   boff  = (int*)  alloc(1024*4);
  float* tmp_u = (float*)alloc((size_t)HYP*D*4);
  float* tmp_i = (float*)alloc((size_t)HYP*D*4);   // adjacent to tmp_u

  // CSR {col,val} pairs overlaid on out's hgnn[l=1] region (free until the last GEMMs)
  int2*  pair_s = (int2*)(out + OUT_PAIR);
  float* hsum   = out;                             // fp32 hidden-sum accumulator

  hipMemsetAsync(cnt, 0, (size_t)N_NODES*4, stream);
  k_init<<<9375, 256, 0, stream>>>(user_emb, item_emb, h_bf, hsum);

  // hyper = bf16(emb) @ bf16(w)   (A = h_bf, built by k_init)
  k_gemm_tall<64,128,false,false><<<N_USERS/32, 256, 0, stream>>>(h_bf, user_w, hyper,
                                                                  nullptr, nullptr, nullptr);
  k_gemm_tall<64,128,false,false><<<N_ITEMS/32, 256, 0, stream>>>(h_bf + (size_t)N_USERS*D, item_w,
                                                                  hyper + (size_t)N_USERS*HYP,
                                                                  nullptr, nullptr, nullptr);
  // CSR build (pattern reused by both layers)
  k_hist<<<(NNZ+255)/256, 256, 0, stream>>>(adj_rows, cnt);
  int nb1 = (N_NODES+1023)/1024;
  k_scan1<<<nb1, 1024, 0, stream>>>(cnt, rowptr, bsum);
  k_scan2<<<1, 1024, 0, stream>>>(bsum, boff, nb1);
  k_scan3<<<(N_NODES+255)/256, 256, 0, stream>>>(cnt, rowptr, boff, cursor);
  k_scatter<<<(NNZ+255)/256, 256, 0, stream>>>(adj_rows, adj_cols, adj_vals, cursor, pair_s);

  for (int l = 0; l < 2; ++l){
    hipMemsetAsync(tmp_u, 0, (size_t)2*HYP*D*4, stream);  // zero tmp_u and tmp_i
    k_spmm<<<N_NODES/4, 256, 0, stream>>>(rowptr, pair_s, h_bf,
                                          out + OUT_GCN0 + (size_t)l*SZL);
    k_step3<<<(N_USERS+511)/512, 256, 0, stream>>>(hyper, h_bf, tmp_u, N_USERS);
    k_step3<<<(N_ITEMS+511)/512, 256, 0, stream>>>(hyper + (size_t)N_USERS*HYP,
                                                   h_bf + (size_t)N_USERS*D, tmp_i, N_ITEMS);
    const float* gcnL = out + OUT_GCN0 + (size_t)l*SZL;
    float*       hgL  = out + OUT_HG0  + (size_t)l*SZL;
    // hg GEMM + fused epilogue (h = gcn+hg; hsum += h; h_bf = bf16(h))
    k_gemm_tall<128,64,true,true><<<N_USERS/32, 256, 0, stream>>>(
        hyper, tmp_u, hgL, gcnL, hsum, h_bf);
    k_gemm_tall<128,64,true,true><<<N_ITEMS/32, 256, 0, stream>>>(
        hyper + (size_t)N_USERS*HYP, tmp_i,
        hgL  + (size_t)N_USERS*D,
        gcnL + (size_t)N_USERS*D,
        hsum + (size_t)N_USERS*D,
        h_bf + (size_t)N_USERS*D);
  }
}

// Round 2
// 1426.445 us; speedup vs baseline: 1.1378x; 1.1378x over previous
//
#include <hip/hip_runtime.h>

typedef unsigned short u16;
typedef unsigned int u32;

#define N_USERS 100000
#define N_ITEMS 200000
#define N_NODES 300000
#define D 64
#define HYP 128
#define NNZ 4000000

// out is 96M fp32 elems: [user_out|item_out|gcn_hidden(2)|hgnn_hidden(2)]
constexpr long long SZL      = 19200000LL;        // one 300000x64 tensor
constexpr long long OUT_GCN0 = SZL;               // gcn_hidden base
constexpr long long OUT_HG0  = 3*SZL;             // hgnn_hidden base
// CSR {col,val} pairs overlaid on hgnn[l=1] region [4*SZL,5*SZL): written only
// by the final two GEMMs, which launch after the last SpMM read of the pairs.
constexpr long long OUT_PAIR = 4*SZL;
// rank_e (NNZ ints, 16MB) overlaid on gcn_hidden[l=1] region [2*SZL,3*SZL):
// consumed by k_place during CSR build, long before layer-1 SpMM writes there.
constexpr long long OUT_RANK = 2*SZL;

typedef __attribute__((ext_vector_type(8))) short short8;
typedef __attribute__((ext_vector_type(4))) float f32x4;

__device__ __forceinline__ float bf2f(u16 u){ u32 i = ((u32)u) << 16; return __builtin_bit_cast(float, i); }
__device__ __forceinline__ u16 f2bf(float f){
  u32 i = __builtin_bit_cast(u32, f);
  return (u16)((i + 0x7FFFu + ((i >> 16) & 1u)) >> 16);
}

// emb (fp32) -> h_bf (bf16), hsum (fp32, == out[0:SZL)). 8 elems/thread.
__global__ void k_init(const float* __restrict__ ue, const float* __restrict__ ie,
                       u16* __restrict__ h_bf, float* __restrict__ hsum){
  int t = blockIdx.x*256 + threadIdx.x;
  int base = t*8;
  const float* src = (base < N_USERS*D) ? (ue + base) : (ie + (base - N_USERS*D));
  float4 v0 = *(const float4*)(src);
  float4 v1 = *(const float4*)(src + 4);
  *(float4*)(hsum + base)     = v0;
  *(float4*)(hsum + base + 4) = v1;
  uint4 p;
  p.x = (u32)f2bf(v0.x) | ((u32)f2bf(v0.y)<<16);
  p.y = (u32)f2bf(v0.z) | ((u32)f2bf(v0.w)<<16);
  p.z = (u32)f2bf(v1.x) | ((u32)f2bf(v1.y)<<16);
  p.w = (u32)f2bf(v1.z) | ((u32)f2bf(v1.w)<<16);
  *(uint4*)(h_bf + base) = p;
}

// C[M x N] = A[M x K] @ B[K x N]; A bf16 row-major, B fp32 staged in LDS as bf16,
// C fp32 (C32) or bf16. 32 rows/block, 4 waves.
// FUSE (requires C32): also performs the layer epilogue on the same rows:
//   h = gcn + hg; hsum += h; hbf = bf16(h)   — saves re-reading hg from HBM.
template<int K, int N, bool C32, bool FUSE>
__global__ __launch_bounds__(256) void k_gemm_tall(const u16* __restrict__ A,
                                                   const float* __restrict__ B,
                                                   void* __restrict__ Cv,
                                                   const float* __restrict__ gcn,
                                                   float* __restrict__ hsum,
                                                   u16* __restrict__ hbf){
  constexpr int SROW = N + 2;                 // padded u16 stride (odd dword stride)
  __shared__ u32 blds[K*SROW/2];
  constexpr int PAIRS = K*N/2;
  for (int p = threadIdx.x; p < PAIRS; p += 256){
    int k = p/(N/2), c2 = p%(N/2);
    float f0 = B[2*p], f1 = B[2*p+1];
    blds[k*(SROW/2) + c2] = (u32)f2bf(f0) | ((u32)f2bf(f1)<<16);
  }
  __syncthreads();
  const u16* bl = (const u16*)blds;
  int wave = threadIdx.x>>6, lane = threadIdx.x&63, q = lane>>4, lm = lane&15;
  constexpr int NT = N/32;
  int mt = wave>>1, ntb = (wave&1)*NT;
  int r0 = blockIdx.x*32;
  f32x4 acc[NT];
  #pragma unroll
  for (int nt=0; nt<NT; ++nt) acc[nt] = (f32x4){0.f,0.f,0.f,0.f};
  const u16* arow = A + (size_t)(r0 + mt*16 + lm)*K + q*8;
  #pragma unroll
  for (int ks = 0; ks < K/32; ++ks){
    short8 a = *(const short8*)(arow + ks*32);
    #pragma unroll
    for (int nt = 0; nt < NT; ++nt){
      short8 b;
      #pragma unroll
      for (int j = 0; j < 8; ++j)
        b[j] = (short)bl[(ks*32 + q*8 + j)*SROW + (ntb+nt)*16 + lm];
      acc[nt] = __builtin_amdgcn_mfma_f32_16x16x32_bf16(a, b, acc[nt], 0, 0, 0);
    }
  }
  #pragma unroll
  for (int nt = 0; nt < NT; ++nt)
    #pragma unroll
    for (int r = 0; r < 4; ++r){
      int row = r0 + mt*16 + q*4 + r;       // C/D: col=lane&15, row=quad*4+reg (m89)
      int col = (ntb+nt)*16 + lm;
      size_t idx = (size_t)row*N + col;
      if (C32){
        float hg = acc[nt][r];
        ((float*)Cv)[idx] = hg;
        if (FUSE){
          float hv = gcn[idx] + hg;
          hsum[idx] += hv;
          hbf[idx] = f2bf(hv);
        }
      } else {
        ((u16*)Cv)[idx] = f2bf(acc[nt][r]);
      }
    }
}

// tmp[128x64] += Hyperᵀ[128 x rows] @ H[rows x 64] over a 512-row K-chunk per block.
__global__ __launch_bounds__(256) void k_step3(const u16* __restrict__ Hy,
                                               const u16* __restrict__ Hm,
                                               float* __restrict__ tmp, int rows){
  __shared__ u32 hyl[32*65];   // 32 k-rows x 128 elems, stride 130 u16
  __shared__ u32 hml[32*33];   // 32 k-rows x 64 elems,  stride 66 u16
  const u16* hyl16 = (const u16*)hyl;
  const u16* hml16 = (const u16*)hml;
  int tid = threadIdx.x;
  int wave = tid>>6, lane = tid&63, q = lane>>4, lm = lane&15;
  int k0 = blockIdx.x*512;
  f32x4 acc[2][4];
  #pragma unroll
  for (int i=0;i<2;i++)
    #pragma unroll
    for (int j=0;j<4;j++) acc[i][j] = (f32x4){0.f,0.f,0.f,0.f};
  for (int kk=0; kk<16; ++kk){
    int kb = k0 + kk*32;
    #pragma unroll
    for (int d0=0; d0<8; ++d0){
      int d = d0*256 + tid;
      int kr = d>>6, c2 = d&63, g = kb+kr;
      hyl[kr*65 + c2] = (g < rows) ? ((const u32*)Hy)[(size_t)g*64 + c2] : 0u;
    }
    #pragma unroll
    for (int d0=0; d0<4; ++d0){
      int d = d0*256 + tid;
      int kr = d>>5, c2 = d&31, g = kb+kr;
      hml[kr*33 + c2] = (g < rows) ? ((const u32*)Hm)[(size_t)g*32 + c2] : 0u;
    }
    __syncthreads();
    short8 a[2], b[4];
    #pragma unroll
    for (int ml=0; ml<2; ++ml)
      #pragma unroll
      for (int j=0;j<8;j++)
        a[ml][j] = (short)hyl16[(q*8+j)*130 + (wave*2+ml)*16 + lm];  // A[m][k]=Hy[k][m]
    #pragma unroll
    for (int nt=0; nt<4; ++nt)
      #pragma unroll
      for (int j=0;j<8;j++)
        b[nt][j] = (short)hml16[(q*8+j)*66 + nt*16 + lm];            // B[k][n]=Hm[k][n]
    #pragma unroll
    for (int ml=0; ml<2; ++ml)
      #pragma unroll
      for (int nt=0; nt<4; ++nt)
        acc[ml][nt] = __builtin_amdgcn_mfma_f32_16x16x32_bf16(a[ml], b[nt], acc[ml][nt], 0,0,0);
    __syncthreads();
  }
  #pragma unroll
  for (int ml=0; ml<2; ++ml)
    #pragma unroll
    for (int nt=0; nt<4; ++nt)
      #pragma unroll
      for (int r=0;r<4;r++){
        int m = (wave*2+ml)*16 + q*4 + r;
        int n = nt*16 + lm;
        atomicAdd(&tmp[m*64 + n], acc[ml][nt][r]);
      }
}

// Fused histogram + rank capture: rank_e[e] = #prior edges with same row.
// This is the ONLY pass with value-returning atomics (4M, was 8M across
// hist+scatter). The returned rank is stored SEQUENTIALLY (write-combines).
__global__ void k_rank(const int* __restrict__ rows_, int* __restrict__ cnt,
                       int* __restrict__ rank_e){
  int t = blockIdx.x*256 + threadIdx.x;
  int e = t*4;
  if (e >= NNZ) return;                       // NNZ%4==0: int4 load is safe
  int4 r4 = *(const int4*)(rows_ + e);
  int4 k;
  k.x = atomicAdd(&cnt[min(max(r4.x,0),N_NODES-1)], 1);
  k.y = atomicAdd(&cnt[min(max(r4.y,0),N_NODES-1)], 1);
  k.z = atomicAdd(&cnt[min(max(r4.z,0),N_NODES-1)], 1);
  k.w = atomicAdd(&cnt[min(max(r4.w,0),N_NODES-1)], 1);
  *(int4*)(rank_e + e) = k;
}

__global__ __launch_bounds__(1024) void k_scan1(const int* __restrict__ cnt,
                                                int* __restrict__ rowptr, int* __restrict__ bsum){
  __shared__ int lds[1024];
  int i = blockIdx.x*1024 + threadIdx.x;
  int v = (i < N_NODES) ? cnt[i] : 0;
  lds[threadIdx.x] = v;
  for (int off=1; off<1024; off<<=1){
    __syncthreads();
    int add = (threadIdx.x >= off) ? lds[threadIdx.x-off] : 0;
    __syncthreads();
    lds[threadIdx.x] += add;
  }
  if (i < N_NODES) rowptr[i+1] = lds[threadIdx.x];
  if (threadIdx.x == 1023) bsum[blockIdx.x] = lds[1023];
}

__global__ __launch_bounds__(1024) void k_scan2(const int* __restrict__ bsum,
                                                int* __restrict__ boff, int nb){
  __shared__ int lds[1024];
  int t = threadIdx.x;
  int v = (t < nb) ? bsum[t] : 0;
  lds[t] = v;
  for (int off=1; off<1024; off<<=1){
    __syncthreads();
    int add = (t >= off) ? lds[t-off] : 0;
    __syncthreads();
    lds[t] += add;
  }
  if (t < nb) boff[t] = lds[t] - v;   // exclusive offsets
}

__global__ void k_scan3(const int* __restrict__ cnt, int* __restrict__ rowptr,
                        const int* __restrict__ boff){
  int i = blockIdx.x*256 + threadIdx.x;
  if (i == 0) rowptr[0] = 0;
  if (i < N_NODES)
    rowptr[i+1] = rowptr[i+1] + boff[i>>10];
}

// Atomic-free placement: p = rowptr[row] + precomputed rank. One 8B AoS store
// per edge; nothing in the chain waits on an atomic return.
__global__ void k_place(const int* __restrict__ rows_, const int* __restrict__ cols_,
                        const float* __restrict__ vals_, const int* __restrict__ rank_e,
                        const int* __restrict__ rowptr, int2* __restrict__ pair_s){
  int t = blockIdx.x*256 + threadIdx.x;
  int e = t*4;
  if (e >= NNZ) return;
  int4 r4 = *(const int4*)(rows_ + e);
  int4 k4 = *(const int4*)(rank_e + e);
  int4 c4 = *(const int4*)(cols_ + e);
  float4 v4 = *(const float4*)(vals_ + e);
  int p;
  p = rowptr[min(max(r4.x,0),N_NODES-1)] + k4.x; p = min(max(p,0),NNZ-1);
  pair_s[p] = make_int2(c4.x, __float_as_int(v4.x));
  p = rowptr[min(max(r4.y,0),N_NODES-1)] + k4.y; p = min(max(p,0),NNZ-1);
  pair_s[p] = make_int2(c4.y, __float_as_int(v4.y));
  p = rowptr[min(max(r4.z,0),N_NODES-1)] + k4.z; p = min(max(p,0),NNZ-1);
  pair_s[p] = make_int2(c4.z, __float_as_int(v4.z));
  p = rowptr[min(max(r4.w,0),N_NODES-1)] + k4.w; p = min(max(p,0),NNZ-1);
  pair_s[p] = make_int2(c4.w, __float_as_int(v4.w));
}

// One wave per row; pairs read coalesced, broadcast via shfl so gathers pipeline.
__global__ __launch_bounds__(256) void k_spmm(const int* __restrict__ rp,
                                              const int2* __restrict__ ps,
                                              const u16* __restrict__ h,
                                              float* __restrict__ gout){
  int r = blockIdx.x*4 + (threadIdx.x>>6);
  int lane = threadIdx.x & 63;
  int beg = rp[r], end = rp[r+1];
  float acc = 0.f;
  for (int base = beg; base < end; base += 64){
    int c = 0; float v = 0.f;
    if (base + lane < end){ int2 pv = ps[base+lane]; c = pv.x; v = __int_as_float(pv.y); }
    int n = end - base; if (n > 64) n = 64;
    for (int e = 0; e < n; ++e){
      int ce = __shfl(c, e);
      float ve = __shfl(v, e);
      acc += ve * bf2f(h[(size_t)ce*64 + lane]);
    }
  }
  gout[(size_t)r*64 + lane] = acc;
}

extern "C" void kernel_launch(void* const* d_in, const int* in_sizes, int n_in,
                              void* d_out, int out_size, void* d_ws, size_t ws_size,
                              hipStream_t stream) {
  const float* user_emb = (const float*)d_in[0];
  const float* item_emb = (const float*)d_in[1];
  const float* user_w   = (const float*)d_in[2];
  const float* item_w   = (const float*)d_in[3];
  const float* adj_vals = (const float*)d_in[4];
  const int* adj_rows = (const int*)d_in[5];
  const int* adj_cols = (const int*)d_in[6];
  float* out = (float*)d_out;

  // ws usage (≈119 MB): hyper 76.8M + h_bf 38.4M + CSR misc ~2.5M
  char* w = (char*)d_ws;
  auto alloc = [&](size_t b){ void* p = (void*)w; w += (b + 255) & ~(size_t)255; return p; };
  u16*   hyper = (u16*)  alloc((size_t)N_NODES*HYP*2);
  u16*   h_bf  = (u16*)  alloc((size_t)N_NODES*D*2);
  int*   cnt   = (int*)  alloc((size_t)N_NODES*4);
  int*   rowptr= (int*)  alloc((size_t)(N_NODES+1)*4);
  int*   bsum  = (int*)  alloc(1024*4);
  int*   boff  = (int*)  alloc(1024*4);
  float* tmp_u = (float*)alloc((size_t)HYP*D*4);
  float* tmp_i = (float*)alloc((size_t)HYP*D*4);   // adjacent to tmp_u

  // Overlays on out (regions free until noted launch):
  int2*  pair_s = (int2*)(out + OUT_PAIR);         // hgnn l=1: free until last GEMMs
  int*   rank_e = (int*) (out + OUT_RANK);         // gcn l=1: free until layer-1 spmm
  float* hsum   = out;                             // fp32 hidden-sum accumulator

  hipMemsetAsync(cnt, 0, (size_t)N_NODES*4, stream);
  k_init<<<9375, 256, 0, stream>>>(user_emb, item_emb, h_bf, hsum);

  // hyper = bf16(emb) @ bf16(w)   (A = h_bf, built by k_init)
  k_gemm_tall<64,128,false,false><<<N_USERS/32, 256, 0, stream>>>(h_bf, user_w, hyper,
                                                                  nullptr, nullptr, nullptr);
  k_gemm_tall<64,128,false,false><<<N_ITEMS/32, 256, 0, stream>>>(h_bf + (size_t)N_USERS*D, item_w,
                                                                  hyper + (size_t)N_USERS*HYP,
                                                                  nullptr, nullptr, nullptr);
  // CSR build (pattern reused by both layers): rank-fused hist -> scan -> place
  int nbE4 = (NNZ/4 + 255)/256;
  k_rank<<<nbE4, 256, 0, stream>>>(adj_rows, cnt, rank_e);
  int nb1 = (N_NODES+1023)/1024;
  k_scan1<<<nb1, 1024, 0, stream>>>(cnt, rowptr, bsum);
  k_scan2<<<1, 1024, 0, stream>>>(bsum, boff, nb1);
  k_scan3<<<(N_NODES+255)/256, 256, 0, stream>>>(cnt, rowptr, boff);
  k_place<<<nbE4, 256, 0, stream>>>(adj_rows, adj_cols, adj_vals, rank_e, rowptr, pair_s);

  for (int l = 0; l < 2; ++l){
    hipMemsetAsync(tmp_u, 0, (size_t)2*HYP*D*4, stream);  // zero tmp_u and tmp_i
    k_spmm<<<N_NODES/4, 256, 0, stream>>>(rowptr, pair_s, h_bf,
                                          out + OUT_GCN0 + (size_t)l*SZL);
    k_step3<<<(N_USERS+511)/512, 256, 0, stream>>>(hyper, h_bf, tmp_u, N_USERS);
    k_step3<<<(N_ITEMS+511)/512, 256, 0, stream>>>(hyper + (size_t)N_USERS*HYP,
                                                   h_bf + (size_t)N_USERS*D, tmp_i, N_ITEMS);
    const float* gcnL = out + OUT_GCN0 + (size_t)l*SZL;
    float*       hgL  = out + OUT_HG0  + (size_t)l*SZL;
    // hg GEMM + fused epilogue (h = gcn+hg; hsum += h; h_bf = bf16(h))
    k_gemm_tall<128,64,true,true><<<N_USERS/32, 256, 0, stream>>>(
        hyper, tmp_u, hgL, gcnL, hsum, h_bf);
    k_gemm_tall<128,64,true,true><<<N_ITEMS/32, 256, 0, stream>>>(
        hyper + (size_t)N_USERS*HYP, tmp_i,
        hgL  + (size_t)N_USERS*D,
        gcnL + (size_t)N_USERS*D,
        hsum + (size_t)N_USERS*D,
        h_bf + (size_t)N_USERS*D);
  }
}

// Round 3
// 1172.988 us; speedup vs baseline: 1.3836x; 1.2161x over previous
//
#include <hip/hip_runtime.h>

typedef unsigned short u16;
typedef unsigned int u32;

#define N_USERS 100000
#define N_ITEMS 200000
#define N_NODES 300000
#define D 64
#define HYP 128
#define NNZ 4000000

// out is 96M fp32 elems: [user_out|item_out|gcn_hidden(2)|hgnn_hidden(2)]
constexpr long long SZL      = 19200000LL;        // one 300000x64 tensor
constexpr long long OUT_GCN0 = SZL;               // gcn_hidden base
constexpr long long OUT_HG0  = 3*SZL;             // hgnn_hidden base
// CSR {col,val} pairs overlaid on hgnn[l=1] region [4*SZL,5*SZL): written only
// by the final two GEMMs, which launch after the last SpMM read of the pairs.
constexpr long long OUT_PAIR = 4*SZL;
// rank_e (NNZ ints, 16MB) overlaid on gcn_hidden[l=1] region [2*SZL,3*SZL):
// consumed by k_place during CSR build, long before layer-1 SpMM writes there.
constexpr long long OUT_RANK = 2*SZL;

typedef __attribute__((ext_vector_type(8))) short short8;
typedef __attribute__((ext_vector_type(4))) float f32x4;

__device__ __forceinline__ float bf2f(u16 u){ u32 i = ((u32)u) << 16; return __builtin_bit_cast(float, i); }
__device__ __forceinline__ u16 f2bf(float f){
  u32 i = __builtin_bit_cast(u32, f);
  return (u16)((i + 0x7FFFu + ((i >> 16) & 1u)) >> 16);
}

// emb (fp32) -> h_bf (bf16), hsum (fp32, == out[0:SZL)). 8 elems/thread.
__global__ void k_init(const float* __restrict__ ue, const float* __restrict__ ie,
                       u16* __restrict__ h_bf, float* __restrict__ hsum){
  int t = blockIdx.x*256 + threadIdx.x;
  int base = t*8;
  const float* src = (base < N_USERS*D) ? (ue + base) : (ie + (base - N_USERS*D));
  float4 v0 = *(const float4*)(src);
  float4 v1 = *(const float4*)(src + 4);
  *(float4*)(hsum + base)     = v0;
  *(float4*)(hsum + base + 4) = v1;
  uint4 p;
  p.x = (u32)f2bf(v0.x) | ((u32)f2bf(v0.y)<<16);
  p.y = (u32)f2bf(v0.z) | ((u32)f2bf(v0.w)<<16);
  p.z = (u32)f2bf(v1.x) | ((u32)f2bf(v1.y)<<16);
  p.w = (u32)f2bf(v1.z) | ((u32)f2bf(v1.w)<<16);
  *(uint4*)(h_bf + base) = p;
}

// C[M x N] = A[M x K] @ B[K x N]; A bf16 row-major, B fp32 staged in LDS as bf16,
// C fp32 (C32) or bf16. 32 rows/block, 4 waves.
// FUSE (requires C32): also performs the layer epilogue on the same rows:
//   h = gcn + hg; hsum += h; hbf = bf16(h)   — saves re-reading hg from HBM.
template<int K, int N, bool C32, bool FUSE>
__global__ __launch_bounds__(256) void k_gemm_tall(const u16* __restrict__ A,
                                                   const float* __restrict__ B,
                                                   void* __restrict__ Cv,
                                                   const float* __restrict__ gcn,
                                                   float* __restrict__ hsum,
                                                   u16* __restrict__ hbf){
  constexpr int SROW = N + 2;                 // padded u16 stride (odd dword stride)
  __shared__ u32 blds[K*SROW/2];
  constexpr int PAIRS = K*N/2;
  for (int p = threadIdx.x; p < PAIRS; p += 256){
    int k = p/(N/2), c2 = p%(N/2);
    float f0 = B[2*p], f1 = B[2*p+1];
    blds[k*(SROW/2) + c2] = (u32)f2bf(f0) | ((u32)f2bf(f1)<<16);
  }
  __syncthreads();
  const u16* bl = (const u16*)blds;
  int wave = threadIdx.x>>6, lane = threadIdx.x&63, q = lane>>4, lm = lane&15;
  constexpr int NT = N/32;
  int mt = wave>>1, ntb = (wave&1)*NT;
  int r0 = blockIdx.x*32;
  f32x4 acc[NT];
  #pragma unroll
  for (int nt=0; nt<NT; ++nt) acc[nt] = (f32x4){0.f,0.f,0.f,0.f};
  const u16* arow = A + (size_t)(r0 + mt*16 + lm)*K + q*8;
  #pragma unroll
  for (int ks = 0; ks < K/32; ++ks){
    short8 a = *(const short8*)(arow + ks*32);
    #pragma unroll
    for (int nt = 0; nt < NT; ++nt){
      short8 b;
      #pragma unroll
      for (int j = 0; j < 8; ++j)
        b[j] = (short)bl[(ks*32 + q*8 + j)*SROW + (ntb+nt)*16 + lm];
      acc[nt] = __builtin_amdgcn_mfma_f32_16x16x32_bf16(a, b, acc[nt], 0, 0, 0);
    }
  }
  #pragma unroll
  for (int nt = 0; nt < NT; ++nt)
    #pragma unroll
    for (int r = 0; r < 4; ++r){
      int row = r0 + mt*16 + q*4 + r;       // C/D: col=lane&15, row=quad*4+reg (m89)
      int col = (ntb+nt)*16 + lm;
      size_t idx = (size_t)row*N + col;
      if (C32){
        float hg = acc[nt][r];
        ((float*)Cv)[idx] = hg;
        if (FUSE){
          float hv = gcn[idx] + hg;
          hsum[idx] += hv;
          hbf[idx] = f2bf(hv);
        }
      } else {
        ((u16*)Cv)[idx] = f2bf(acc[nt][r]);
      }
    }
}

// tmp[128x64] += Hyperᵀ[128 x rows] @ H[rows x 64] over a 512-row K-chunk per block.
__global__ __launch_bounds__(256) void k_step3(const u16* __restrict__ Hy,
                                               const u16* __restrict__ Hm,
                                               float* __restrict__ tmp, int rows){
  __shared__ u32 hyl[32*65];   // 32 k-rows x 128 elems, stride 130 u16
  __shared__ u32 hml[32*33];   // 32 k-rows x 64 elems,  stride 66 u16
  const u16* hyl16 = (const u16*)hyl;
  const u16* hml16 = (const u16*)hml;
  int tid = threadIdx.x;
  int wave = tid>>6, lane = tid&63, q = lane>>4, lm = lane&15;
  int k0 = blockIdx.x*512;
  f32x4 acc[2][4];
  #pragma unroll
  for (int i=0;i<2;i++)
    #pragma unroll
    for (int j=0;j<4;j++) acc[i][j] = (f32x4){0.f,0.f,0.f,0.f};
  for (int kk=0; kk<16; ++kk){
    int kb = k0 + kk*32;
    #pragma unroll
    for (int d0=0; d0<8; ++d0){
      int d = d0*256 + tid;
      int kr = d>>6, c2 = d&63, g = kb+kr;
      hyl[kr*65 + c2] = (g < rows) ? ((const u32*)Hy)[(size_t)g*64 + c2] : 0u;
    }
    #pragma unroll
    for (int d0=0; d0<4; ++d0){
      int d = d0*256 + tid;
      int kr = d>>5, c2 = d&31, g = kb+kr;
      hml[kr*33 + c2] = (g < rows) ? ((const u32*)Hm)[(size_t)g*32 + c2] : 0u;
    }
    __syncthreads();
    short8 a[2], b[4];
    #pragma unroll
    for (int ml=0; ml<2; ++ml)
      #pragma unroll
      for (int j=0;j<8;j++)
        a[ml][j] = (short)hyl16[(q*8+j)*130 + (wave*2+ml)*16 + lm];  // A[m][k]=Hy[k][m]
    #pragma unroll
    for (int nt=0; nt<4; ++nt)
      #pragma unroll
      for (int j=0;j<8;j++)
        b[nt][j] = (short)hml16[(q*8+j)*66 + nt*16 + lm];            // B[k][n]=Hm[k][n]
    #pragma unroll
    for (int ml=0; ml<2; ++ml)
      #pragma unroll
      for (int nt=0; nt<4; ++nt)
        acc[ml][nt] = __builtin_amdgcn_mfma_f32_16x16x32_bf16(a[ml], b[nt], acc[ml][nt], 0,0,0);
    __syncthreads();
  }
  #pragma unroll
  for (int ml=0; ml<2; ++ml)
    #pragma unroll
    for (int nt=0; nt<4; ++nt)
      #pragma unroll
      for (int r=0;r<4;r++){
        int m = (wave*2+ml)*16 + q*4 + r;
        int n = nt*16 + lm;
        atomicAdd(&tmp[m*64 + n], acc[ml][nt][r]);
      }
}

// Fused histogram + rank capture: rank_e[e] = #prior edges with same row.
__global__ void k_rank(const int* __restrict__ rows_, int* __restrict__ cnt,
                       int* __restrict__ rank_e){
  int t = blockIdx.x*256 + threadIdx.x;
  int e = t*4;
  if (e >= NNZ) return;                       // NNZ%4==0: int4 load is safe
  int4 r4 = *(const int4*)(rows_ + e);
  int4 k;
  k.x = atomicAdd(&cnt[min(max(r4.x,0),N_NODES-1)], 1);
  k.y = atomicAdd(&cnt[min(max(r4.y,0),N_NODES-1)], 1);
  k.z = atomicAdd(&cnt[min(max(r4.z,0),N_NODES-1)], 1);
  k.w = atomicAdd(&cnt[min(max(r4.w,0),N_NODES-1)], 1);
  *(int4*)(rank_e + e) = k;
}

__global__ __launch_bounds__(1024) void k_scan1(const int* __restrict__ cnt,
                                                int* __restrict__ rowptr, int* __restrict__ bsum){
  __shared__ int lds[1024];
  int i = blockIdx.x*1024 + threadIdx.x;
  int v = (i < N_NODES) ? cnt[i] : 0;
  lds[threadIdx.x] = v;
  for (int off=1; off<1024; off<<=1){
    __syncthreads();
    int add = (threadIdx.x >= off) ? lds[threadIdx.x-off] : 0;
    __syncthreads();
    lds[threadIdx.x] += add;
  }
  if (i < N_NODES) rowptr[i+1] = lds[threadIdx.x];
  if (threadIdx.x == 1023) bsum[blockIdx.x] = lds[1023];
}

__global__ __launch_bounds__(1024) void k_scan2(const int* __restrict__ bsum,
                                                int* __restrict__ boff, int nb){
  __shared__ int lds[1024];
  int t = threadIdx.x;
  int v = (t < nb) ? bsum[t] : 0;
  lds[t] = v;
  for (int off=1; off<1024; off<<=1){
    __syncthreads();
    int add = (t >= off) ? lds[t-off] : 0;
    __syncthreads();
    lds[t] += add;
  }
  if (t < nb) boff[t] = lds[t] - v;   // exclusive offsets
}

__global__ void k_scan3(const int* __restrict__ cnt, int* __restrict__ rowptr,
                        const int* __restrict__ boff){
  int i = blockIdx.x*256 + threadIdx.x;
  if (i == 0) rowptr[0] = 0;
  if (i < N_NODES)
    rowptr[i+1] = rowptr[i+1] + boff[i>>10];
}

// Atomic-free placement: p = rowptr[row] + precomputed rank. One 8B AoS store
// per edge; nothing in the chain waits on an atomic return.
__global__ void k_place(const int* __restrict__ rows_, const int* __restrict__ cols_,
                        const float* __restrict__ vals_, const int* __restrict__ rank_e,
                        const int* __restrict__ rowptr, int2* __restrict__ pair_s){
  int t = blockIdx.x*256 + threadIdx.x;
  int e = t*4;
  if (e >= NNZ) return;
  int4 r4 = *(const int4*)(rows_ + e);
  int4 k4 = *(const int4*)(rank_e + e);
  int4 c4 = *(const int4*)(cols_ + e);
  float4 v4 = *(const float4*)(vals_ + e);
  int p;
  p = rowptr[min(max(r4.x,0),N_NODES-1)] + k4.x; p = min(max(p,0),NNZ-1);
  pair_s[p] = make_int2(c4.x, __float_as_int(v4.x));
  p = rowptr[min(max(r4.y,0),N_NODES-1)] + k4.y; p = min(max(p,0),NNZ-1);
  pair_s[p] = make_int2(c4.y, __float_as_int(v4.y));
  p = rowptr[min(max(r4.z,0),N_NODES-1)] + k4.z; p = min(max(p,0),NNZ-1);
  pair_s[p] = make_int2(c4.z, __float_as_int(v4.z));
  p = rowptr[min(max(r4.w,0),N_NODES-1)] + k4.w; p = min(max(p,0),NNZ-1);
  pair_s[p] = make_int2(c4.w, __float_as_int(v4.w));
}

// One wave per row. Edge loop unrolled 8-wide so each wave keeps 8 independent
// h-row gathers in flight (was 1 -> pure latency serialization at ~40 cy/edge).
// No tail loop: lanes past `end` hold c=0,v=0, so padded slots gather the
// always-cached row 0 and contribute 0.0f. shfl index e+j <= 63 always
// (e is a multiple of 8 below n<=64).
__global__ __launch_bounds__(256) void k_spmm(const int* __restrict__ rp,
                                              const int2* __restrict__ ps,
                                              const u16* __restrict__ h,
                                              float* __restrict__ gout){
  int r = blockIdx.x*4 + (threadIdx.x>>6);
  int lane = threadIdx.x & 63;
  int beg = rp[r], end = rp[r+1];
  float acc = 0.f;
  for (int base = beg; base < end; base += 64){
    int c = 0; float v = 0.f;
    if (base + lane < end){ int2 pv = ps[base+lane]; c = pv.x; v = __int_as_float(pv.y); }
    int n = end - base; if (n > 64) n = 64;
    for (int e = 0; e < n; e += 8){
      int ce[8]; float ve[8]; float hv[8];
      #pragma unroll
      for (int j = 0; j < 8; ++j){
        ce[j] = __shfl(c, e + j);
        ve[j] = __shfl(v, e + j);
      }
      #pragma unroll
      for (int j = 0; j < 8; ++j)
        hv[j] = bf2f(h[(size_t)ce[j]*64 + lane]);   // 8 independent gathers in flight
      #pragma unroll
      for (int j = 0; j < 8; ++j)
        acc += ve[j] * hv[j];
    }
  }
  gout[(size_t)r*64 + lane] = acc;
}

extern "C" void kernel_launch(void* const* d_in, const int* in_sizes, int n_in,
                              void* d_out, int out_size, void* d_ws, size_t ws_size,
                              hipStream_t stream) {
  const float* user_emb = (const float*)d_in[0];
  const float* item_emb = (const float*)d_in[1];
  const float* user_w   = (const float*)d_in[2];
  const float* item_w   = (const float*)d_in[3];
  const float* adj_vals = (const float*)d_in[4];
  const int* adj_rows = (const int*)d_in[5];
  const int* adj_cols = (const int*)d_in[6];
  float* out = (float*)d_out;

  // ws usage (≈119 MB): hyper 76.8M + h_bf 38.4M + CSR misc ~2.5M
  char* w = (char*)d_ws;
  auto alloc = [&](size_t b){ void* p = (void*)w; w += (b + 255) & ~(size_t)255; return p; };
  u16*   hyper = (u16*)  alloc((size_t)N_NODES*HYP*2);
  u16*   h_bf  = (u16*)  alloc((size_t)N_NODES*D*2);
  int*   cnt   = (int*)  alloc((size_t)N_NODES*4);
  int*   rowptr= (int*)  alloc((size_t)(N_NODES+1)*4);
  int*   bsum  = (int*)  alloc(1024*4);
  int*   boff  = (int*)  alloc(1024*4);
  float* tmp_u = (float*)alloc((size_t)HYP*D*4);
  float* tmp_i = (float*)alloc((size_t)HYP*D*4);   // adjacent to tmp_u

  // Overlays on out (regions free until noted launch):
  int2*  pair_s = (int2*)(out + OUT_PAIR);         // hgnn l=1: free until last GEMMs
  int*   rank_e = (int*) (out + OUT_RANK);         // gcn l=1: free until layer-1 spmm
  float* hsum   = out;                             // fp32 hidden-sum accumulator

  hipMemsetAsync(cnt, 0, (size_t)N_NODES*4, stream);
  k_init<<<9375, 256, 0, stream>>>(user_emb, item_emb, h_bf, hsum);

  // hyper = bf16(emb) @ bf16(w)   (A = h_bf, built by k_init)
  k_gemm_tall<64,128,false,false><<<N_USERS/32, 256, 0, stream>>>(h_bf, user_w, hyper,
                                                                  nullptr, nullptr, nullptr);
  k_gemm_tall<64,128,false,false><<<N_ITEMS/32, 256, 0, stream>>>(h_bf + (size_t)N_USERS*D, item_w,
                                                                  hyper + (size_t)N_USERS*HYP,
                                                                  nullptr, nullptr, nullptr);
  // CSR build (pattern reused by both layers): rank-fused hist -> scan -> place
  int nbE4 = (NNZ/4 + 255)/256;
  k_rank<<<nbE4, 256, 0, stream>>>(adj_rows, cnt, rank_e);
  int nb1 = (N_NODES+1023)/1024;
  k_scan1<<<nb1, 1024, 0, stream>>>(cnt, rowptr, bsum);
  k_scan2<<<1, 1024, 0, stream>>>(bsum, boff, nb1);
  k_scan3<<<(N_NODES+255)/256, 256, 0, stream>>>(cnt, rowptr, boff);
  k_place<<<nbE4, 256, 0, stream>>>(adj_rows, adj_cols, adj_vals, rank_e, rowptr, pair_s);

  for (int l = 0; l < 2; ++l){
    hipMemsetAsync(tmp_u, 0, (size_t)2*HYP*D*4, stream);  // zero tmp_u and tmp_i
    k_spmm<<<N_NODES/4, 256, 0, stream>>>(rowptr, pair_s, h_bf,
                                          out + OUT_GCN0 + (size_t)l*SZL);
    k_step3<<<(N_USERS+511)/512, 256, 0, stream>>>(hyper, h_bf, tmp_u, N_USERS);
    k_step3<<<(N_ITEMS+511)/512, 256, 0, stream>>>(hyper + (size_t)N_USERS*HYP,
                                                   h_bf + (size_t)N_USERS*D, tmp_i, N_ITEMS);
    const float* gcnL = out + OUT_GCN0 + (size_t)l*SZL;
    float*       hgL  = out + OUT_HG0  + (size_t)l*SZL;
    // hg GEMM + fused epilogue (h = gcn+hg; hsum += h; h_bf = bf16(h))
    k_gemm_tall<128,64,true,true><<<N_USERS/32, 256, 0, stream>>>(
        hyper, tmp_u, hgL, gcnL, hsum, h_bf);
    k_gemm_tall<128,64,true,true><<<N_ITEMS/32, 256, 0, stream>>>(
        hyper + (size_t)N_USERS*HYP, tmp_i,
        hgL  + (size_t)N_USERS*D,
        gcnL + (size_t)N_USERS*D,
        hsum + (size_t)N_USERS*D,
        h_bf + (size_t)N_USERS*D);
  }
}

// Round 4
// 1149.030 us; speedup vs baseline: 1.4125x; 1.0209x over previous
//
#include <hip/hip_runtime.h>

typedef unsigned short u16;
typedef unsigned int u32;
typedef unsigned long long u64;

#define N_USERS 100000
#define N_ITEMS 200000
#define N_NODES 300000
#define D 64
#define HYP 128
#define NNZ 4000000

// out is 96M fp32 elems: [user_out|item_out|gcn_hidden(2)|hgnn_hidden(2)]
constexpr long long SZL      = 19200000LL;        // one 300000x64 tensor
constexpr long long OUT_GCN0 = SZL;               // gcn_hidden base
constexpr long long OUT_HG0  = 3*SZL;             // hgnn_hidden base
// CSR {col,val} pairs overlaid on hgnn[l=1] region [4*SZL,5*SZL): written only
// by the final fused GEMM, which launches after the last SpMM read of the pairs.
constexpr long long OUT_PAIR = 4*SZL;
// rank_e (NNZ ints, 16MB) overlaid on gcn_hidden[l=1] region [2*SZL,3*SZL):
// consumed by k_place during CSR build, long before layer-1 SpMM writes there.
constexpr long long OUT_RANK = 2*SZL;

// k_layer block partition: step3 blocks FIRST (so they co-reside with the
// spmm flood), then spmm blocks.
#define S3_CHUNK 512
constexpr int NB_S3U = (N_USERS + S3_CHUNK - 1)/S3_CHUNK;  // 196
constexpr int NB_S3I = (N_ITEMS + S3_CHUNK - 1)/S3_CHUNK;  // 391
constexpr int NB_S3  = NB_S3U + NB_S3I;                    // 587
constexpr int UB64   = N_USERS/32;                         // 3125 user blocks

typedef __attribute__((ext_vector_type(8))) short short8;
typedef __attribute__((ext_vector_type(4))) float f32x4;

__device__ __forceinline__ float bf2f(u16 u){ u32 i = ((u32)u) << 16; return __builtin_bit_cast(float, i); }
__device__ __forceinline__ u16 f2bf(float f){
  u32 i = __builtin_bit_cast(u32, f);
  return (u16)((i + 0x7FFFu + ((i >> 16) & 1u)) >> 16);
}

// emb (fp32) -> h_bf (bf16), hsum (fp32, == out[0:SZL)). 8 elems/thread.
__global__ void k_init(const float* __restrict__ ue, const float* __restrict__ ie,
                       u16* __restrict__ h_bf, float* __restrict__ hsum){
  int t = blockIdx.x*256 + threadIdx.x;
  int base = t*8;
  const float* src = (base < N_USERS*D) ? (ue + base) : (ie + (base - N_USERS*D));
  float4 v0 = *(const float4*)(src);
  float4 v1 = *(const float4*)(src + 4);
  *(float4*)(hsum + base)     = v0;
  *(float4*)(hsum + base + 4) = v1;
  uint4 p;
  p.x = (u32)f2bf(v0.x) | ((u32)f2bf(v0.y)<<16);
  p.y = (u32)f2bf(v0.z) | ((u32)f2bf(v0.w)<<16);
  p.z = (u32)f2bf(v1.x) | ((u32)f2bf(v1.y)<<16);
  p.w = (u32)f2bf(v1.z) | ((u32)f2bf(v1.w)<<16);
  *(uint4*)(h_bf + base) = p;
}

// C[M x N] = A[M x K] @ B[K x N]; A bf16 row-major, B fp32 staged in LDS as bf16,
// C fp32 (C32) or bf16. 32 rows/block, 4 waves.
// User+item pair merged into ONE launch: blocks [0,ublocks) = user segment,
// [ublocks, grid) = item segment (own A/C offsets, own B pointer).
// FUSE (requires C32): fused layer epilogue on the same rows:
//   h = gcn + hg; hsum += h; hbf = bf16(h)  — saves re-reading hg from HBM.
//   hg itself is stored nontemporally (pure streaming output, no reuse).
template<int K, int N, bool C32, bool FUSE>
__global__ __launch_bounds__(256) void k_gemm_tall(const u16* __restrict__ A0,
                                                   const float* __restrict__ Bu,
                                                   const float* __restrict__ Bi,
                                                   void* __restrict__ Cv,
                                                   const float* __restrict__ gcn0,
                                                   float* __restrict__ hsum0,
                                                   u16* __restrict__ hbf0,
                                                   int ublocks){
  bool it = (int)blockIdx.x >= ublocks;
  int blk = it ? (int)blockIdx.x - ublocks : (int)blockIdx.x;
  const u16* A = A0 + (it ? (size_t)ublocks*32*K : 0);
  const float* B = it ? Bi : Bu;
  size_t co = it ? (size_t)ublocks*32*N : 0;   // C/gcn/hsum/hbf element offset

  constexpr int SROW = N + 2;                 // padded u16 stride (odd dword stride)
  __shared__ u32 blds[K*SROW/2];
  constexpr int PAIRS = K*N/2;
  for (int p = threadIdx.x; p < PAIRS; p += 256){
    int k = p/(N/2), c2 = p%(N/2);
    float f0 = B[2*p], f1 = B[2*p+1];
    blds[k*(SROW/2) + c2] = (u32)f2bf(f0) | ((u32)f2bf(f1)<<16);
  }
  __syncthreads();
  const u16* bl = (const u16*)blds;
  int wave = threadIdx.x>>6, lane = threadIdx.x&63, q = lane>>4, lm = lane&15;
  constexpr int NT = N/32;
  int mt = wave>>1, ntb = (wave&1)*NT;
  int r0 = blk*32;
  f32x4 acc[NT];
  #pragma unroll
  for (int nt=0; nt<NT; ++nt) acc[nt] = (f32x4){0.f,0.f,0.f,0.f};
  const u16* arow = A + (size_t)(r0 + mt*16 + lm)*K + q*8;
  #pragma unroll
  for (int ks = 0; ks < K/32; ++ks){
    short8 a = *(const short8*)(arow + ks*32);
    #pragma unroll
    for (int nt = 0; nt < NT; ++nt){
      short8 b;
      #pragma unroll
      for (int j = 0; j < 8; ++j)
        b[j] = (short)bl[(ks*32 + q*8 + j)*SROW + (ntb+nt)*16 + lm];
      acc[nt] = __builtin_amdgcn_mfma_f32_16x16x32_bf16(a, b, acc[nt], 0, 0, 0);
    }
  }
  #pragma unroll
  for (int nt = 0; nt < NT; ++nt)
    #pragma unroll
    for (int r = 0; r < 4; ++r){
      int row = r0 + mt*16 + q*4 + r;       // C/D: col=lane&15, row=quad*4+reg (m89)
      int col = (ntb+nt)*16 + lm;
      size_t idx = co + (size_t)row*N + col;
      if (C32){
        float hg = acc[nt][r];
        if (FUSE){
          __builtin_nontemporal_store(hg, &((float*)Cv)[idx]);  // hg: streaming, no reuse
          float hv = gcn0[idx] + hg;
          hsum0[idx] += hv;
          hbf0[idx] = f2bf(hv);
        } else {
          ((float*)Cv)[idx] = hg;
        }
      } else {
        ((u16*)Cv)[idx] = f2bf(acc[nt][r]);
      }
    }
}

// tmp[128x64] += Hyperᵀ[128 x rows] @ H[rows x 64] over a 512-row K-chunk.
__device__ __forceinline__ void step3_body(const u16* __restrict__ Hy,
                                           const u16* __restrict__ Hm,
                                           float* __restrict__ tmp, int rows, int k0,
                                           u32* __restrict__ lds){
  u32* hyl = lds;            // 32 k-rows x 128 elems, stride 130 u16 (65 u32)
  u32* hml = lds + 32*65;    // 32 k-rows x 64 elems,  stride 66 u16 (33 u32)
  const u16* hyl16 = (const u16*)hyl;
  const u16* hml16 = (const u16*)hml;
  int tid = threadIdx.x;
  int wave = tid>>6, lane = tid&63, q = lane>>4, lm = lane&15;
  f32x4 acc[2][4];
  #pragma unroll
  for (int i=0;i<2;i++)
    #pragma unroll
    for (int j=0;j<4;j++) acc[i][j] = (f32x4){0.f,0.f,0.f,0.f};
  for (int kk=0; kk<S3_CHUNK/32; ++kk){
    int kb = k0 + kk*32;
    #pragma unroll
    for (int d0=0; d0<8; ++d0){
      int d = d0*256 + tid;
      int kr = d>>6, c2 = d&63, g = kb+kr;
      hyl[kr*65 + c2] = (g < rows) ? ((const u32*)Hy)[(size_t)g*64 + c2] : 0u;
    }
    #pragma unroll
    for (int d0=0; d0<4; ++d0){
      int d = d0*256 + tid;
      int kr = d>>5, c2 = d&31, g = kb+kr;
      hml[kr*33 + c2] = (g < rows) ? ((const u32*)Hm)[(size_t)g*32 + c2] : 0u;
    }
    __syncthreads();
    short8 a[2], b[4];
    #pragma unroll
    for (int ml=0; ml<2; ++ml)
      #pragma unroll
      for (int j=0;j<8;j++)
        a[ml][j] = (short)hyl16[(q*8+j)*130 + (wave*2+ml)*16 + lm];  // A[m][k]=Hy[k][m]
    #pragma unroll
    for (int nt=0; nt<4; ++nt)
      #pragma unroll
      for (int j=0;j<8;j++)
        b[nt][j] = (short)hml16[(q*8+j)*66 + nt*16 + lm];            // B[k][n]=Hm[k][n]
    #pragma unroll
    for (int ml=0; ml<2; ++ml)
      #pragma unroll
      for (int nt=0; nt<4; ++nt)
        acc[ml][nt] = __builtin_amdgcn_mfma_f32_16x16x32_bf16(a[ml], b[nt], acc[ml][nt], 0,0,0);
    __syncthreads();
  }
  #pragma unroll
  for (int ml=0; ml<2; ++ml)
    #pragma unroll
    for (int nt=0; nt<4; ++nt)
      #pragma unroll
      for (int r=0;r<4;r++){
        int m = (wave*2+ml)*16 + q*4 + r;
        int n = nt*16 + lm;
        atomicAdd(&tmp[m*64 + n], acc[ml][nt][r]);
      }
}

// Fused per-layer kernel: blocks [0,NB_S3) run step3 (user then item K-chunks),
// blocks [NB_S3, ...) run spmm. step3 (MFMA/latency work) overlaps the spmm
// gather flood (L2-miss throughput-bound, VALU 26%, MFMA 0) — complementary pipes.
__global__ __launch_bounds__(256) void k_layer(const int* __restrict__ rp,
                                               const int2* __restrict__ ps,
                                               const u16* __restrict__ h,
                                               float* __restrict__ gout,
                                               const u16* __restrict__ hyper,
                                               float* __restrict__ tmp){
  __shared__ u32 lds[32*65 + 32*33];
  int bid = blockIdx.x;
  if (bid < NB_S3){
    if (bid < NB_S3U)
      step3_body(hyper, h, tmp, N_USERS, bid*S3_CHUNK, lds);
    else
      step3_body(hyper + (size_t)N_USERS*HYP, h + (size_t)N_USERS*D,
                 tmp + HYP*D, N_ITEMS, (bid - NB_S3U)*S3_CHUNK, lds);
    return;
  }
  // spmm: one wave per row; edge loop unrolled 8-wide (8 independent gathers
  // in flight). Lanes past `end` hold c=0,v=0 -> padded slots gather row 0
  // (always cached) and contribute 0.0f. shfl index e+j <= 63 always.
  int r = (bid - NB_S3)*4 + (threadIdx.x>>6);
  int lane = threadIdx.x & 63;
  int beg = rp[r], end = rp[r+1];
  float acc = 0.f;
  for (int base = beg; base < end; base += 64){
    int c = 0; float v = 0.f;
    if (base + lane < end){ int2 pv = ps[base+lane]; c = pv.x; v = __int_as_float(pv.y); }
    int n = end - base; if (n > 64) n = 64;
    for (int e = 0; e < n; e += 8){
      int ce[8]; float ve[8]; float hv[8];
      #pragma unroll
      for (int j = 0; j < 8; ++j){
        ce[j] = __shfl(c, e + j);
        ve[j] = __shfl(v, e + j);
      }
      #pragma unroll
      for (int j = 0; j < 8; ++j)
        hv[j] = bf2f(h[(size_t)ce[j]*64 + lane]);
      #pragma unroll
      for (int j = 0; j < 8; ++j)
        acc += ve[j] * hv[j];
    }
  }
  gout[(size_t)r*64 + lane] = acc;
}

// Fused histogram + rank capture: rank_e[e] = #prior edges with same row.
__global__ void k_rank(const int* __restrict__ rows_, int* __restrict__ cnt,
                       int* __restrict__ rank_e){
  int t = blockIdx.x*256 + threadIdx.x;
  int e = t*4;
  if (e >= NNZ) return;                       // NNZ%4==0: int4 load is safe
  int4 r4 = *(const int4*)(rows_ + e);
  int4 k;
  k.x = atomicAdd(&cnt[min(max(r4.x,0),N_NODES-1)], 1);
  k.y = atomicAdd(&cnt[min(max(r4.y,0),N_NODES-1)], 1);
  k.z = atomicAdd(&cnt[min(max(r4.z,0),N_NODES-1)], 1);
  k.w = atomicAdd(&cnt[min(max(r4.w,0),N_NODES-1)], 1);
  *(int4*)(rank_e + e) = k;
}

__global__ __launch_bounds__(1024) void k_scan1(const int* __restrict__ cnt,
                                                int* __restrict__ rowptr, int* __restrict__ bsum){
  __shared__ int lds[1024];
  int i = blockIdx.x*1024 + threadIdx.x;
  int v = (i < N_NODES) ? cnt[i] : 0;
  lds[threadIdx.x] = v;
  for (int off=1; off<1024; off<<=1){
    __syncthreads();
    int add = (threadIdx.x >= off) ? lds[threadIdx.x-off] : 0;
    __syncthreads();
    lds[threadIdx.x] += add;
  }
  if (i < N_NODES) rowptr[i+1] = lds[threadIdx.x];
  if (threadIdx.x == 1023) bsum[blockIdx.x] = lds[1023];
}

__global__ __launch_bounds__(1024) void k_scan2(const int* __restrict__ bsum,
                                                int* __restrict__ boff, int nb){
  __shared__ int lds[1024];
  int t = threadIdx.x;
  int v = (t < nb) ? bsum[t] : 0;
  lds[t] = v;
  for (int off=1; off<1024; off<<=1){
    __syncthreads();
    int add = (t >= off) ? lds[t-off] : 0;
    __syncthreads();
    lds[t] += add;
  }
  if (t < nb) boff[t] = lds[t] - v;   // exclusive offsets
}

__global__ void k_scan3(const int* __restrict__ cnt, int* __restrict__ rowptr,
                        const int* __restrict__ boff){
  int i = blockIdx.x*256 + threadIdx.x;
  if (i == 0) rowptr[0] = 0;
  if (i < N_NODES)
    rowptr[i+1] = rowptr[i+1] + boff[i>>10];
}

// Atomic-free placement: p = rowptr[row] + precomputed rank. One 8B packed
// NONTEMPORAL store per edge: random lines have zero reuse, so bypass L2
// allocation (reduces line thrash across the 8 private L2s).
__global__ void k_place(const int* __restrict__ rows_, const int* __restrict__ cols_,
                        const float* __restrict__ vals_, const int* __restrict__ rank_e,
                        const int* __restrict__ rowptr, int2* __restrict__ pair_s){
  int t = blockIdx.x*256 + threadIdx.x;
  int e = t*4;
  if (e >= NNZ) return;
  int4 r4 = *(const int4*)(rows_ + e);
  int4 k4 = *(const int4*)(rank_e + e);
  int4 c4 = *(const int4*)(cols_ + e);
  float4 v4 = *(const float4*)(vals_ + e);
  int p;
  u64 pk;
  p = rowptr[min(max(r4.x,0),N_NODES-1)] + k4.x; p = min(max(p,0),NNZ-1);
  pk = (u64)(u32)c4.x | ((u64)(u32)__float_as_int(v4.x) << 32);
  __builtin_nontemporal_store(pk, (u64*)&pair_s[p]);
  p = rowptr[min(max(r4.y,0),N_NODES-1)] + k4.y; p = min(max(p,0),NNZ-1);
  pk = (u64)(u32)c4.y | ((u64)(u32)__float_as_int(v4.y) << 32);
  __builtin_nontemporal_store(pk, (u64*)&pair_s[p]);
  p = rowptr[min(max(r4.z,0),N_NODES-1)] + k4.z; p = min(max(p,0),NNZ-1);
  pk = (u64)(u32)c4.z | ((u64)(u32)__float_as_int(v4.z) << 32);
  __builtin_nontemporal_store(pk, (u64*)&pair_s[p]);
  p = rowptr[min(max(r4.w,0),N_NODES-1)] + k4.w; p = min(max(p,0),NNZ-1);
  pk = (u64)(u32)c4.w | ((u64)(u32)__float_as_int(v4.w) << 32);
  __builtin_nontemporal_store(pk, (u64*)&pair_s[p]);
}

extern "C" void kernel_launch(void* const* d_in, const int* in_sizes, int n_in,
                              void* d_out, int out_size, void* d_ws, size_t ws_size,
                              hipStream_t stream) {
  const float* user_emb = (const float*)d_in[0];
  const float* item_emb = (const float*)d_in[1];
  const float* user_w   = (const float*)d_in[2];
  const float* item_w   = (const float*)d_in[3];
  const float* adj_vals = (const float*)d_in[4];
  const int* adj_rows = (const int*)d_in[5];
  const int* adj_cols = (const int*)d_in[6];
  float* out = (float*)d_out;

  // ws usage (≈119 MB): hyper 76.8M + h_bf 38.4M + CSR misc ~2.5M
  char* w = (char*)d_ws;
  auto alloc = [&](size_t b){ void* p = (void*)w; w += (b + 255) & ~(size_t)255; return p; };
  u16*   hyper = (u16*)  alloc((size_t)N_NODES*HYP*2);
  u16*   h_bf  = (u16*)  alloc((size_t)N_NODES*D*2);
  int*   cnt   = (int*)  alloc((size_t)N_NODES*4);
  int*   rowptr= (int*)  alloc((size_t)(N_NODES+1)*4);
  int*   bsum  = (int*)  alloc(1024*4);
  int*   boff  = (int*)  alloc(1024*4);
  float* tmp_u = (float*)alloc((size_t)HYP*D*4);   // tmp_i = tmp_u + HYP*D (32KB, 256-aligned)
  float* tmp_i = (float*)alloc((size_t)HYP*D*4);
  (void)tmp_i;

  // Overlays on out (regions free until noted launch):
  int2*  pair_s = (int2*)(out + OUT_PAIR);         // hgnn l=1: free until last fused GEMM
  int*   rank_e = (int*) (out + OUT_RANK);         // gcn l=1: free until layer-1 k_layer
  float* hsum   = out;                             // fp32 hidden-sum accumulator

  hipMemsetAsync(cnt, 0, (size_t)N_NODES*4, stream);
  k_init<<<9375, 256, 0, stream>>>(user_emb, item_emb, h_bf, hsum);

  // hyper = bf16(emb) @ bf16(w): user+item merged into one launch
  k_gemm_tall<64,128,false,false><<<9375, 256, 0, stream>>>(
      h_bf, user_w, item_w, hyper, nullptr, nullptr, nullptr, UB64);

  // CSR build (pattern reused by both layers): rank-fused hist -> scan -> place
  int nbE4 = (NNZ/4 + 255)/256;
  k_rank<<<nbE4, 256, 0, stream>>>(adj_rows, cnt, rank_e);
  int nb1 = (N_NODES+1023)/1024;
  k_scan1<<<nb1, 1024, 0, stream>>>(cnt, rowptr, bsum);
  k_scan2<<<1, 1024, 0, stream>>>(bsum, boff, nb1);
  k_scan3<<<(N_NODES+255)/256, 256, 0, stream>>>(cnt, rowptr, boff);
  k_place<<<nbE4, 256, 0, stream>>>(adj_rows, adj_cols, adj_vals, rank_e, rowptr, pair_s);

  for (int l = 0; l < 2; ++l){
    hipMemsetAsync(tmp_u, 0, (size_t)2*HYP*D*4, stream);  // zero tmp_u and tmp_i
    // spmm + step3(user) + step3(item) in one launch (step3 blocks first)
    k_layer<<<NB_S3 + N_NODES/4, 256, 0, stream>>>(rowptr, pair_s, h_bf,
                                                   out + OUT_GCN0 + (size_t)l*SZL,
                                                   hyper, tmp_u);
    const float* gcnL = out + OUT_GCN0 + (size_t)l*SZL;
    float*       hgL  = out + OUT_HG0  + (size_t)l*SZL;
    // hg GEMM (user+item merged) + fused epilogue (h = gcn+hg; hsum += h; h_bf = bf16(h))
    k_gemm_tall<128,64,true,true><<<9375, 256, 0, stream>>>(
        hyper, tmp_u, tmp_u + HYP*D, hgL, gcnL, hsum, h_bf, UB64);
  }
}

// Round 5
// 1108.460 us; speedup vs baseline: 1.4642x; 1.0366x over previous
//
#include <hip/hip_runtime.h>

typedef unsigned short u16;
typedef unsigned int u32;
typedef unsigned long long u64;

#define N_USERS 100000
#define N_ITEMS 200000
#define N_NODES 300000
#define D 64
#define HYP 128
#define NNZ 4000000

// out is 96M fp32 elems: [user_out|item_out|gcn_hidden(2)|hgnn_hidden(2)]
constexpr long long SZL      = 19200000LL;        // one 300000x64 tensor
constexpr long long OUT_GCN0 = SZL;               // gcn_hidden base
constexpr long long OUT_HG0  = 3*SZL;             // hgnn_hidden base
// CSR {col,val} pairs overlaid on hgnn[l=1] region [4*SZL,5*SZL): written only
// by the final fused GEMM (after the last SpMM read of the pairs).
constexpr long long OUT_PAIR = 4*SZL;
// step3 partial tiles (587 x 8192 floats = 19.2MB) overlaid right after pair_s
// in the same hgnn[l=1] region: pair_s occupies 8M floats; partials use the
// next 4.81M; consumed by k_reduce before the final GEMM overwrites hg[1].
constexpr long long OUT_PART = OUT_PAIR + 8000000LL;
// rank_e (NNZ ints, 16MB) overlaid on gcn_hidden[l=1] region [2*SZL,3*SZL):
// consumed by k_f2's place path, long before layer-1 SpMM writes there.
constexpr long long OUT_RANK = 2*SZL;

#define S3_CHUNK 512
constexpr int NB_S3U = (N_USERS + S3_CHUNK - 1)/S3_CHUNK;  // 196
constexpr int NB_S3I = (N_ITEMS + S3_CHUNK - 1)/S3_CHUNK;  // 391
constexpr int NB_S3  = NB_S3U + NB_S3I;                    // 587
constexpr int UB64   = N_USERS/32;                         // 3125 user gemm blocks
constexpr int NB_E4  = (NNZ/4 + 255)/256;                  // 3907 (rank/place blocks)
constexpr int RG_U   = (NB_S3U + 31)/32;                   // 7 reduce groups (user)
constexpr int RG_I   = (NB_S3I + 31)/32;                   // 13 reduce groups (item)

typedef __attribute__((ext_vector_type(8))) short short8;
typedef __attribute__((ext_vector_type(4))) float f32x4;

__device__ __forceinline__ float bf2f(u16 u){ u32 i = ((u32)u) << 16; return __builtin_bit_cast(float, i); }
__device__ __forceinline__ u16 f2bf(float f){
  u32 i = __builtin_bit_cast(u32, f);
  return (u16)((i + 0x7FFFu + ((i >> 16) & 1u)) >> 16);
}

// ---------------- init body: emb (fp32) -> h_bf (bf16), hsum (fp32) ----------
__device__ __forceinline__ void init_body(int t, const float* __restrict__ ue,
                                          const float* __restrict__ ie,
                                          u16* __restrict__ h_bf, float* __restrict__ hsum){
  int base = t*8;
  const float* src = (base < N_USERS*D) ? (ue + base) : (ie + (base - N_USERS*D));
  float4 v0 = *(const float4*)(src);
  float4 v1 = *(const float4*)(src + 4);
  *(float4*)(hsum + base)     = v0;
  *(float4*)(hsum + base + 4) = v1;
  uint4 p;
  p.x = (u32)f2bf(v0.x) | ((u32)f2bf(v0.y)<<16);
  p.y = (u32)f2bf(v0.z) | ((u32)f2bf(v0.w)<<16);
  p.z = (u32)f2bf(v1.x) | ((u32)f2bf(v1.y)<<16);
  p.w = (u32)f2bf(v1.z) | ((u32)f2bf(v1.w)<<16);
  *(uint4*)(h_bf + base) = p;
}

// k_f1: rank blocks first (latency/atomic-bound), init blocks after (pure
// streaming) — independent work overlapping complementary pipes.
__global__ void k_f1(const float* __restrict__ ue, const float* __restrict__ ie,
                     u16* __restrict__ h_bf, float* __restrict__ hsum,
                     const int* __restrict__ rows_, int* __restrict__ cnt,
                     int* __restrict__ rank_e){
  int bid = blockIdx.x;
  if (bid < NB_E4){
    // rank: rank_e[e] = #prior edges with same row (returning atomics,
    // result stored sequentially)
    int t = bid*256 + threadIdx.x;
    int e = t*4;
    if (e >= NNZ) return;                     // NNZ%4==0: int4 load is safe
    int4 r4 = *(const int4*)(rows_ + e);
    int4 k;
    k.x = atomicAdd(&cnt[min(max(r4.x,0),N_NODES-1)], 1);
    k.y = atomicAdd(&cnt[min(max(r4.y,0),N_NODES-1)], 1);
    k.z = atomicAdd(&cnt[min(max(r4.z,0),N_NODES-1)], 1);
    k.w = atomicAdd(&cnt[min(max(r4.w,0),N_NODES-1)], 1);
    *(int4*)(rank_e + e) = k;
    return;
  }
  init_body((bid - NB_E4)*256 + threadIdx.x, ue, ie, h_bf, hsum);
}

// ---------------- GEMM body (shared by k_gemm_tall and k_f2) -----------------
// C[M x N] = A[M x K] @ B[K x N]; A bf16 row-major, B fp32 staged in LDS as
// bf16. 32 rows/block, 4 waves. User+item merged: blocks [0,ublocks) = user,
// rest = item. FUSE: layer epilogue h = gcn+hg; hsum += h; hbf = bf16(h);
// hg stored nontemporally (streaming, no reuse).
template<int K, int N, bool C32, bool FUSE>
__device__ __forceinline__ void gemm_body(int bid, const u16* __restrict__ A0,
                                          const float* __restrict__ Bu,
                                          const float* __restrict__ Bi,
                                          void* __restrict__ Cv,
                                          const float* __restrict__ gcn0,
                                          float* __restrict__ hsum0,
                                          u16* __restrict__ hbf0,
                                          int ublocks, u32* blds){
  bool it = bid >= ublocks;
  int blk = it ? bid - ublocks : bid;
  const u16* A = A0 + (it ? (size_t)ublocks*32*K : 0);
  const float* B = it ? Bi : Bu;
  size_t co = it ? (size_t)ublocks*32*N : 0;   // C/gcn/hsum/hbf element offset

  constexpr int SROW = N + 2;                 // padded u16 stride (odd dword stride)
  constexpr int PAIRS = K*N/2;
  for (int p = threadIdx.x; p < PAIRS; p += 256){
    int k = p/(N/2), c2 = p%(N/2);
    float f0 = B[2*p], f1 = B[2*p+1];
    blds[k*(SROW/2) + c2] = (u32)f2bf(f0) | ((u32)f2bf(f1)<<16);
  }
  __syncthreads();
  const u16* bl = (const u16*)blds;
  int wave = threadIdx.x>>6, lane = threadIdx.x&63, q = lane>>4, lm = lane&15;
  constexpr int NT = N/32;
  int mt = wave>>1, ntb = (wave&1)*NT;
  int r0 = blk*32;
  f32x4 acc[NT];
  #pragma unroll
  for (int nt=0; nt<NT; ++nt) acc[nt] = (f32x4){0.f,0.f,0.f,0.f};
  const u16* arow = A + (size_t)(r0 + mt*16 + lm)*K + q*8;
  #pragma unroll
  for (int ks = 0; ks < K/32; ++ks){
    short8 a = *(const short8*)(arow + ks*32);
    #pragma unroll
    for (int nt = 0; nt < NT; ++nt){
      short8 b;
      #pragma unroll
      for (int j = 0; j < 8; ++j)
        b[j] = (short)bl[(ks*32 + q*8 + j)*SROW + (ntb+nt)*16 + lm];
      acc[nt] = __builtin_amdgcn_mfma_f32_16x16x32_bf16(a, b, acc[nt], 0, 0, 0);
    }
  }
  #pragma unroll
  for (int nt = 0; nt < NT; ++nt)
    #pragma unroll
    for (int r = 0; r < 4; ++r){
      int row = r0 + mt*16 + q*4 + r;       // C/D: col=lane&15, row=quad*4+reg (m89)
      int col = (ntb+nt)*16 + lm;
      size_t idx = co + (size_t)row*N + col;
      if (C32){
        float hg = acc[nt][r];
        if (FUSE){
          __builtin_nontemporal_store(hg, &((float*)Cv)[idx]);  // hg: streaming
          float hv = gcn0[idx] + hg;
          hsum0[idx] += hv;
          hbf0[idx] = f2bf(hv);
        } else {
          ((float*)Cv)[idx] = hg;
        }
      } else {
        ((u16*)Cv)[idx] = f2bf(acc[nt][r]);
      }
    }
}

template<int K, int N, bool C32, bool FUSE>
__global__ __launch_bounds__(256) void k_gemm_tall(const u16* __restrict__ A0,
                                                   const float* __restrict__ Bu,
                                                   const float* __restrict__ Bi,
                                                   void* __restrict__ Cv,
                                                   const float* __restrict__ gcn0,
                                                   float* __restrict__ hsum0,
                                                   u16* __restrict__ hbf0,
                                                   int ublocks){
  __shared__ u32 blds[K*(N+2)/2];
  gemm_body<K,N,C32,FUSE>((int)blockIdx.x, A0, Bu, Bi, Cv, gcn0, hsum0, hbf0, ublocks, blds);
}

// k_f2: place blocks first (random-store-bound), then the 64->128 hyper GEMM
// blocks (MFMA/LDS-bound) — independent, complementary pipes.
__global__ __launch_bounds__(256) void k_f2(const int* __restrict__ rows_,
                                            const int* __restrict__ cols_,
                                            const float* __restrict__ vals_,
                                            const int* __restrict__ rank_e,
                                            const int* __restrict__ rowptr,
                                            int2* __restrict__ pair_s,
                                            const u16* __restrict__ h_bf,
                                            const float* __restrict__ user_w,
                                            const float* __restrict__ item_w,
                                            u16* __restrict__ hyper){
  __shared__ u32 blds[64*(128+2)/2];
  int bid = blockIdx.x;
  if (bid < NB_E4){
    // place: p = rowptr[row] + rank. Atomic-free; one 8B packed nontemporal
    // store per edge (random lines, zero reuse -> bypass L2 allocation).
    int t = bid*256 + threadIdx.x;
    int e = t*4;
    if (e >= NNZ) return;
    int4 r4 = *(const int4*)(rows_ + e);
    int4 k4 = *(const int4*)(rank_e + e);
    int4 c4 = *(const int4*)(cols_ + e);
    float4 v4 = *(const float4*)(vals_ + e);
    int p; u64 pk;
    p = rowptr[min(max(r4.x,0),N_NODES-1)] + k4.x; p = min(max(p,0),NNZ-1);
    pk = (u64)(u32)c4.x | ((u64)(u32)__float_as_int(v4.x) << 32);
    __builtin_nontemporal_store(pk, (u64*)&pair_s[p]);
    p = rowptr[min(max(r4.y,0),N_NODES-1)] + k4.y; p = min(max(p,0),NNZ-1);
    pk = (u64)(u32)c4.y | ((u64)(u32)__float_as_int(v4.y) << 32);
    __builtin_nontemporal_store(pk, (u64*)&pair_s[p]);
    p = rowptr[min(max(r4.z,0),N_NODES-1)] + k4.z; p = min(max(p,0),NNZ-1);
    pk = (u64)(u32)c4.z | ((u64)(u32)__float_as_int(v4.z) << 32);
    __builtin_nontemporal_store(pk, (u64*)&pair_s[p]);
    p = rowptr[min(max(r4.w,0),N_NODES-1)] + k4.w; p = min(max(p,0),NNZ-1);
    pk = (u64)(u32)c4.w | ((u64)(u32)__float_as_int(v4.w) << 32);
    __builtin_nontemporal_store(pk, (u64*)&pair_s[p]);
    return;
  }
  gemm_body<64,128,false,false>(bid - NB_E4, h_bf, user_w, item_w, hyper,
                                nullptr, nullptr, nullptr, UB64, blds);
}

// ---------------- step3: partial tiles, NO hot atomics -----------------------
// part[bid][128x64] = Hyperᵀ[128 x chunk] @ H[chunk x 64] for one 512-row
// K-chunk. Previously each block atomicAdd'ed 8192 floats onto 16K hot
// addresses (4.8M contended RMWs ~ 100+ us); now nontemporal private stores,
// summed by k_reduce.
__device__ __forceinline__ void step3_body(const u16* __restrict__ Hy,
                                           const u16* __restrict__ Hm,
                                           float* __restrict__ outp, int rows, int k0,
                                           u32* __restrict__ lds){
  u32* hyl = lds;            // 32 k-rows x 128 elems, stride 130 u16 (65 u32)
  u32* hml = lds + 32*65;    // 32 k-rows x 64 elems,  stride 66 u16 (33 u32)
  const u16* hyl16 = (const u16*)hyl;
  const u16* hml16 = (const u16*)hml;
  int tid = threadIdx.x;
  int wave = tid>>6, lane = tid&63, q = lane>>4, lm = lane&15;
  f32x4 acc[2][4];
  #pragma unroll
  for (int i=0;i<2;i++)
    #pragma unroll
    for (int j=0;j<4;j++) acc[i][j] = (f32x4){0.f,0.f,0.f,0.f};
  for (int kk=0; kk<S3_CHUNK/32; ++kk){
    int kb = k0 + kk*32;
    #pragma unroll
    for (int d0=0; d0<8; ++d0){
      int d = d0*256 + tid;
      int kr = d>>6, c2 = d&63, g = kb+kr;
      hyl[kr*65 + c2] = (g < rows) ? ((const u32*)Hy)[(size_t)g*64 + c2] : 0u;
    }
    #pragma unroll
    for (int d0=0; d0<4; ++d0){
      int d = d0*256 + tid;
      int kr = d>>5, c2 = d&31, g = kb+kr;
      hml[kr*33 + c2] = (g < rows) ? ((const u32*)Hm)[(size_t)g*32 + c2] : 0u;
    }
    __syncthreads();
    short8 a[2], b[4];
    #pragma unroll
    for (int ml=0; ml<2; ++ml)
      #pragma unroll
      for (int j=0;j<8;j++)
        a[ml][j] = (short)hyl16[(q*8+j)*130 + (wave*2+ml)*16 + lm];  // A[m][k]=Hy[k][m]
    #pragma unroll
    for (int nt=0; nt<4; ++nt)
      #pragma unroll
      for (int j=0;j<8;j++)
        b[nt][j] = (short)hml16[(q*8+j)*66 + nt*16 + lm];            // B[k][n]=Hm[k][n]
    #pragma unroll
    for (int ml=0; ml<2; ++ml)
      #pragma unroll
      for (int nt=0; nt<4; ++nt)
        acc[ml][nt] = __builtin_amdgcn_mfma_f32_16x16x32_bf16(a[ml], b[nt], acc[ml][nt], 0,0,0);
    __syncthreads();
  }
  #pragma unroll
  for (int ml=0; ml<2; ++ml)
    #pragma unroll
    for (int nt=0; nt<4; ++nt)
      #pragma unroll
      for (int r=0;r<4;r++){
        int m = (wave*2+ml)*16 + q*4 + r;
        int n = nt*16 + lm;
        __builtin_nontemporal_store(acc[ml][nt][r], &outp[m*64 + n]);
      }
}

__global__ __launch_bounds__(256) void k_step3(const u16* __restrict__ hyper,
                                               const u16* __restrict__ h,
                                               float* __restrict__ part){
  __shared__ u32 lds[32*65 + 32*33];
  int bid = blockIdx.x;
  float* outp = part + (size_t)bid*8192;
  if (bid < NB_S3U)
    step3_body(hyper, h, outp, N_USERS, bid*S3_CHUNK, lds);
  else
    step3_body(hyper + (size_t)N_USERS*HYP, h + (size_t)N_USERS*D,
               outp, N_ITEMS, (bid - NB_S3U)*S3_CHUNK, lds);
}

// Sum the 587 partial tiles into tmp[2][8192]. Each thread sums a 32-block
// group for one column, then one atomicAdd (164K atomics total - trivial).
__global__ void k_reduce(const float* __restrict__ part, float* __restrict__ tmp){
  int cb = blockIdx.x & 31;           // 32 col-blocks x 256 threads = 8192 cols
  int g  = blockIdx.x >> 5;           // group 0..RG_U+RG_I-1
  int j  = cb*256 + threadIdx.x;
  int b0, b1; float* dst;
  if (g < RG_U){ b0 = g*32;            b1 = min(b0+32, NB_S3U); dst = tmp; }
  else         { b0 = NB_S3U + (g-RG_U)*32; b1 = min(b0+32, NB_S3); dst = tmp + HYP*D; }
  float s = 0.f;
  for (int b = b0; b < b1; ++b) s += part[(size_t)b*8192 + j];
  atomicAdd(&dst[j], s);
}

// ---------------- scans (unchanged) ------------------------------------------
__global__ __launch_bounds__(1024) void k_scan1(const int* __restrict__ cnt,
                                                int* __restrict__ rowptr, int* __restrict__ bsum){
  __shared__ int lds[1024];
  int i = blockIdx.x*1024 + threadIdx.x;
  int v = (i < N_NODES) ? cnt[i] : 0;
  lds[threadIdx.x] = v;
  for (int off=1; off<1024; off<<=1){
    __syncthreads();
    int add = (threadIdx.x >= off) ? lds[threadIdx.x-off] : 0;
    __syncthreads();
    lds[threadIdx.x] += add;
  }
  if (i < N_NODES) rowptr[i+1] = lds[threadIdx.x];
  if (threadIdx.x == 1023) bsum[blockIdx.x] = lds[1023];
}

__global__ __launch_bounds__(1024) void k_scan2(const int* __restrict__ bsum,
                                                int* __restrict__ boff, int nb){
  __shared__ int lds[1024];
  int t = threadIdx.x;
  int v = (t < nb) ? bsum[t] : 0;
  lds[t] = v;
  for (int off=1; off<1024; off<<=1){
    __syncthreads();
    int add = (t >= off) ? lds[t-off] : 0;
    __syncthreads();
    lds[t] += add;
  }
  if (t < nb) boff[t] = lds[t] - v;   // exclusive offsets
}

__global__ void k_scan3(const int* __restrict__ cnt, int* __restrict__ rowptr,
                        const int* __restrict__ boff){
  int i = blockIdx.x*256 + threadIdx.x;
  if (i == 0) rowptr[0] = 0;
  if (i < N_NODES)
    rowptr[i+1] = rowptr[i+1] + boff[i>>10];
}

// ---------------- spmm (standalone again; 8-deep gather pipeline) ------------
__global__ __launch_bounds__(256) void k_spmm(const int* __restrict__ rp,
                                              const int2* __restrict__ ps,
                                              const u16* __restrict__ h,
                                              float* __restrict__ gout){
  int r = blockIdx.x*4 + (threadIdx.x>>6);
  int lane = threadIdx.x & 63;
  int beg = rp[r], end = rp[r+1];
  float acc = 0.f;
  for (int base = beg; base < end; base += 64){
    int c = 0; float v = 0.f;
    if (base + lane < end){ int2 pv = ps[base+lane]; c = pv.x; v = __int_as_float(pv.y); }
    int n = end - base; if (n > 64) n = 64;
    for (int e = 0; e < n; e += 8){
      int ce[8]; float ve[8]; float hv[8];
      #pragma unroll
      for (int j = 0; j < 8; ++j){
        ce[j] = __shfl(c, e + j);
        ve[j] = __shfl(v, e + j);
      }
      #pragma unroll
      for (int j = 0; j < 8; ++j)
        hv[j] = bf2f(h[(size_t)ce[j]*64 + lane]);   // 8 independent gathers
      #pragma unroll
      for (int j = 0; j < 8; ++j)
        acc += ve[j] * hv[j];
    }
  }
  gout[(size_t)r*64 + lane] = acc;
}

extern "C" void kernel_launch(void* const* d_in, const int* in_sizes, int n_in,
                              void* d_out, int out_size, void* d_ws, size_t ws_size,
                              hipStream_t stream) {
  const float* user_emb = (const float*)d_in[0];
  const float* item_emb = (const float*)d_in[1];
  const float* user_w   = (const float*)d_in[2];
  const float* item_w   = (const float*)d_in[3];
  const float* adj_vals = (const float*)d_in[4];
  const int* adj_rows = (const int*)d_in[5];
  const int* adj_cols = (const int*)d_in[6];
  float* out = (float*)d_out;

  // ws usage (~118 MB): hyper 76.8M + h_bf 38.4M + CSR misc ~2.5M
  char* w = (char*)d_ws;
  auto alloc = [&](size_t b){ void* p = (void*)w; w += (b + 255) & ~(size_t)255; return p; };
  u16*   hyper = (u16*)  alloc((size_t)N_NODES*HYP*2);
  u16*   h_bf  = (u16*)  alloc((size_t)N_NODES*D*2);
  int*   cnt   = (int*)  alloc((size_t)N_NODES*4);
  int*   rowptr= (int*)  alloc((size_t)(N_NODES+1)*4);
  int*   bsum  = (int*)  alloc(1024*4);
  int*   boff  = (int*)  alloc(1024*4);
  float* tmp_u = (float*)alloc((size_t)HYP*D*4);   // tmp_i = tmp_u + HYP*D
  float* tmp_i = (float*)alloc((size_t)HYP*D*4);
  (void)tmp_i;

  // Overlays on out (regions free until noted launch):
  int2*  pair_s = (int2*)(out + OUT_PAIR);         // hgnn[1]: free until last fused GEMM
  float* part   = out + OUT_PART;                  // after pair_s, same region
  int*   rank_e = (int*) (out + OUT_RANK);         // gcn[1]: free until layer-1 spmm
  float* hsum   = out;                             // fp32 hidden-sum accumulator

  hipMemsetAsync(cnt, 0, (size_t)N_NODES*4, stream);
  // rank (atomic-latency) || init (streaming)
  k_f1<<<NB_E4 + 9375, 256, 0, stream>>>(user_emb, item_emb, h_bf, hsum,
                                         adj_rows, cnt, rank_e);
  int nb1 = (N_NODES+1023)/1024;
  k_scan1<<<nb1, 1024, 0, stream>>>(cnt, rowptr, bsum);
  k_scan2<<<1, 1024, 0, stream>>>(bsum, boff, nb1);
  k_scan3<<<(N_NODES+255)/256, 256, 0, stream>>>(cnt, rowptr, boff);
  // place (random stores) || hyper = bf16(emb) @ bf16(w) (MFMA)
  k_f2<<<NB_E4 + 9375, 256, 0, stream>>>(adj_rows, adj_cols, adj_vals, rank_e,
                                         rowptr, pair_s, h_bf, user_w, item_w, hyper);

  for (int l = 0; l < 2; ++l){
    hipMemsetAsync(tmp_u, 0, (size_t)2*HYP*D*4, stream);  // zero tmp_u and tmp_i
    k_spmm<<<N_NODES/4, 256, 0, stream>>>(rowptr, pair_s, h_bf,
                                          out + OUT_GCN0 + (size_t)l*SZL);
    k_step3<<<NB_S3, 256, 0, stream>>>(hyper, h_bf, part);
    k_reduce<<<32*(RG_U+RG_I), 256, 0, stream>>>(part, tmp_u);
    const float* gcnL = out + OUT_GCN0 + (size_t)l*SZL;
    float*       hgL  = out + OUT_HG0  + (size_t)l*SZL;
    // hg GEMM (user+item merged) + fused epilogue (h = gcn+hg; hsum += h; h_bf = bf16(h))
    k_gemm_tall<128,64,true,true><<<9375, 256, 0, stream>>>(
        hyper, tmp_u, tmp_u + HYP*D, hgL, gcnL, hsum, h_bf, UB64);
  }
}